// Round 4
// baseline (116.275 us; speedup 1.0000x reference)
//
#include <hip/hip_runtime.h>
#include <hip/hip_bf16.h>

typedef short v8s __attribute__((ext_vector_type(8)));
typedef float v4f __attribute__((ext_vector_type(4)));

#define NB 4
#define NC 32
#define NT 1024
#define NU 32
#define NH 128
#define KF 192   // 6 feature groups x 32 u

static __device__ __forceinline__ unsigned short f2bf(float f) {
    unsigned int u = __float_as_uint(f);
    return (unsigned short)((u + 0x7fffu + ((u >> 16) & 1u)) >> 16);  // RNE
}

// ---------------- Kernel A: q/k feature maps + bf16 copies ----------------
// tanh(z) ~= z + C1 z^3 + C2 z^5;  e_ij = sum_u Wa_u tanh(q_iu + k_ju)
// factors as sum_p A_p(q) * B_p(k) over 6 groups (binomial expansion).
__global__ __launch_bounds__(256) void prep_kernel(
    const float* __restrict__ x, const float* __restrict__ Wt,
    const float* __restrict__ Wx, const float* __restrict__ bh,
    const float* __restrict__ Wa,
    const float* __restrict__ W1, const float* __restrict__ W2,
    unsigned short* __restrict__ Fq, unsigned short* __restrict__ Fk,
    unsigned short* __restrict__ xbf,
    unsigned short* __restrict__ w1bf, unsigned short* __restrict__ w2bf)
{
    int bid = blockIdx.x, tid = threadIdx.x;
    if (bid < 512) {
        int gid = (bid << 8) + tid;
        int row = gid >> 5, u = gid & 31;        // row = b*1024 + t
        int b = row >> 10, t = row & 1023;
        const float* xp = x + (size_t)b * (NC * NT) + t;
        float aq = 0.f, ak = 0.f;
        #pragma unroll
        for (int c = 0; c < NC; ++c) {
            float xv = xp[c * NT];
            aq = fmaf(xv, Wt[c * NU + u], aq);
            ak = fmaf(xv, Wx[c * NU + u], ak);
        }
        float q = aq + bh[u];
        float k = ak;
        float wa = Wa[u];
        const float C1 = -0.33333334f, C2 = 0.13333334f;
        float q2 = q * q, q3 = q2 * q, q4 = q2 * q2, q5 = q4 * q;
        unsigned short* fq = Fq + (size_t)row * KF + u;
        fq[0]   = f2bf(wa * fmaf(C2, q5, fmaf(C1, q3, q)));
        fq[32]  = f2bf(wa * fmaf(5.f * C2, q4, fmaf(3.f * C1, q2, 1.f)));
        fq[64]  = f2bf(wa * fmaf(10.f * C2, q3, 3.f * C1 * q));
        fq[96]  = f2bf(wa * fmaf(10.f * C2, q2, C1));
        fq[128] = f2bf(wa * (5.f * C2 * q));
        fq[160] = f2bf(wa * C2);
        float k2 = k * k, k3 = k2 * k, k4 = k2 * k2, k5 = k4 * k;
        unsigned short* fk = Fk + (size_t)row * KF + u;
        fk[0]   = 0x3F80;            // 1.0 bf16
        fk[32]  = f2bf(k);
        fk[64]  = f2bf(k2);
        fk[96]  = f2bf(k3);
        fk[128] = f2bf(k4);
        fk[160] = f2bf(k5);
    } else if (bid < 640) {                      // x -> bf16, same [b][c][t] layout
        int base = ((bid - 512) << 10) + (tid << 2);
        float4 xv = *(const float4*)(x + base);
        xbf[base]     = f2bf(xv.x);
        xbf[base + 1] = f2bf(xv.y);
        xbf[base + 2] = f2bf(xv.z);
        xbf[base + 3] = f2bf(xv.w);
    } else if (bid < 642) {                      // W1 (128x32) -> bf16
        int base = ((bid - 640) << 11) + (tid << 3);
        #pragma unroll
        for (int i = 0; i < 8; ++i) w1bf[base + i] = f2bf(W1[base + i]);
    } else {                                     // W2 (32x128) -> bf16
        int base = ((bid - 642) << 11) + (tid << 3);
        #pragma unroll
        for (int i = 0; i < 8; ++i) w2bf[base + i] = f2bf(W2[base + i]);
    }
}

// ---------------- Kernel B: e = Fq @ Fk^T (MFMA), softmax, write a ----------------
// Block = 512 threads (8 waves) owns 16 rows x 1024 cols; wave w owns cols
// [w*128, w*128+128) as 8 n-tiles of 16x16x32 MFMA, K=192 (6 k-steps).
__global__ __launch_bounds__(512) void score_kernel(
    const unsigned short* __restrict__ Fq, const unsigned short* __restrict__ Fk,
    float* __restrict__ a_out, unsigned short* __restrict__ abf)
{
    __shared__ float redA[8][16];
    __shared__ float redB[8][16];
    const int tid = threadIdx.x;
    const int lane = tid & 63, w = tid >> 6;
    const int col = lane & 15, g = lane >> 4;
    const int row0 = blockIdx.x << 4;            // global row = b*1024 + t0
    const int b = row0 >> 10;
    const int jbase = w << 7;

    // A-fragments: lane holds A[m=col][k=g*8+j], 6 k-steps, reused over 8 n-tiles
    v8s afr[6];
    {
        const unsigned short* ap = Fq + (size_t)(row0 + col) * KF + (g << 3);
        #pragma unroll
        for (int ks = 0; ks < 6; ++ks) afr[ks] = *(const v8s*)(ap + (ks << 5));
    }

    v4f acc[8];
    #pragma unroll
    for (int nt = 0; nt < 8; ++nt) acc[nt] = (v4f){0.f, 0.f, 0.f, 0.f};
    {
        const unsigned short* bp = Fk + ((size_t)(b << 10) + jbase + col) * KF + (g << 3);
        #pragma unroll
        for (int nt = 0; nt < 8; ++nt) {
            const unsigned short* bpn = bp + nt * 16 * KF;
            #pragma unroll
            for (int ks = 0; ks < 6; ++ks) {
                v8s bfr = *(const v8s*)(bpn + (ks << 5));
                acc[nt] = __builtin_amdgcn_mfma_f32_16x16x32_bf16(afr[ks], bfr, acc[nt], 0, 0, 0);
            }
        }
    }

    // ---- softmax over j (rows held as row=g*4+r, col=w*128+nt*16+col) ----
    float m4[4];
    #pragma unroll
    for (int r = 0; r < 4; ++r) {
        float m = acc[0][r];
        #pragma unroll
        for (int nt = 1; nt < 8; ++nt) m = fmaxf(m, acc[nt][r]);
        #pragma unroll
        for (int o = 1; o < 16; o <<= 1) m = fmaxf(m, __shfl_xor(m, o));
        m4[r] = m;
    }
    if (col == 0) {
        #pragma unroll
        for (int r = 0; r < 4; ++r) redA[w][(g << 2) + r] = m4[r];
    }
    __syncthreads();
    float mfin[4];
    #pragma unroll
    for (int r = 0; r < 4; ++r) {
        float m = -1e30f;
        #pragma unroll
        for (int w2 = 0; w2 < 8; ++w2) m = fmaxf(m, redA[w2][(g << 2) + r]);
        mfin[r] = m;
    }
    float s4[4] = {0.f, 0.f, 0.f, 0.f};
    #pragma unroll
    for (int nt = 0; nt < 8; ++nt) {
        #pragma unroll
        for (int r = 0; r < 4; ++r) {
            float ev = __expf(acc[nt][r] - mfin[r]);
            acc[nt][r] = ev;
            s4[r] += ev;
        }
    }
    #pragma unroll
    for (int r = 0; r < 4; ++r) {
        #pragma unroll
        for (int o = 1; o < 16; o <<= 1) s4[r] += __shfl_xor(s4[r], o);
    }
    if (col == 0) {
        #pragma unroll
        for (int r = 0; r < 4; ++r) redB[w][(g << 2) + r] = s4[r];
    }
    __syncthreads();
    float inv[4];
    #pragma unroll
    for (int r = 0; r < 4; ++r) {
        float S = 0.f;
        #pragma unroll
        for (int w2 = 0; w2 < 8; ++w2) S += redB[w2][(g << 2) + r];
        inv[r] = 1.f / (S + 1e-5f);
    }

    #pragma unroll
    for (int r = 0; r < 4; ++r) {
        size_t base = ((size_t)(row0 + (g << 2) + r) << 10) + jbase + col;
        #pragma unroll
        for (int nt = 0; nt < 8; ++nt) {
            float av = acc[nt][r] * inv[r];
            a_out[base + (nt << 4)] = av;
            abf[base + (nt << 4)]   = f2bf(av);
        }
    }
}

// ---------------- Kernel C: v = a@xt (MFMA, 4-wave K-split) -> LN1 -> FFN -> LN2 ----
// Block = 256 threads (4 waves), one 16-row tile. 256 blocks = 4 b * 64 tiles.
__global__ __launch_bounds__(256) void tail_kernel(
    const unsigned short* __restrict__ abf,
    const unsigned short* __restrict__ xbf,
    const float* __restrict__ x,
    const float* __restrict__ gamma1, const float* __restrict__ beta1,
    const unsigned short* __restrict__ w1bf, const float* __restrict__ b1,
    const unsigned short* __restrict__ w2bf, const float* __restrict__ b2,
    const float* __restrict__ gamma2, const float* __restrict__ beta2,
    float* __restrict__ y2out)
{
    __shared__ __attribute__((aligned(16))) float red[4 * 64 * 9];          // padded, 9.2 KB
    __shared__ __attribute__((aligned(16))) unsigned short ysh[16 * 40];    // y bf16
    __shared__ __attribute__((aligned(16))) unsigned short h1sh[16 * 136];  // h1 bf16
    const int tid = threadIdx.x;
    const int lane = tid & 63;
    const int wv = tid >> 6;
    const int col = lane & 15, g = lane >> 4;
    const int b = blockIdx.x >> 6;
    const int t0 = (blockIdx.x & 63) << 4;

    // --- v partial: wave wv covers K-chunks [wv*8, wv*8+8) of 32 ---
    v4f acc0 = {0.f, 0.f, 0.f, 0.f}, acc1 = {0.f, 0.f, 0.f, 0.f};
    {
        const unsigned short* ar  = abf + (((size_t)((b << 10) + t0 + col)) << 10) + (g << 3);
        const unsigned short* xr0 = xbf + (((size_t)((b << 5) + col)) << 10) + (g << 3);
        const unsigned short* xr1 = xr0 + (16 << 10);
        const int it0 = wv << 3;
        #pragma unroll
        for (int i = 0; i < 8; ++i) {
            int it = it0 + i;
            v8s af  = *(const v8s*)(ar  + (it << 5));
            v8s bf0 = *(const v8s*)(xr0 + (it << 5));
            v8s bf1 = *(const v8s*)(xr1 + (it << 5));
            acc0 = __builtin_amdgcn_mfma_f32_16x16x32_bf16(af, bf0, acc0, 0, 0, 0);
            acc1 = __builtin_amdgcn_mfma_f32_16x16x32_bf16(af, bf1, acc1, 0, 0, 0);
        }
    }
    {
        float* rp = red + ((wv << 6) + lane) * 9;
        #pragma unroll
        for (int r = 0; r < 4; ++r) { rp[r] = acc0[r]; rp[4 + r] = acc1[r]; }
    }
    __syncthreads();

    float y0[4], y1[4];
    if (wv == 0) {
        #pragma unroll
        for (int w = 1; w < 4; ++w) {
            const float* rp = red + ((w << 6) + lane) * 9;
            #pragma unroll
            for (int r = 0; r < 4; ++r) { acc0[r] += rp[r]; acc1[r] += rp[4 + r]; }
        }
        // --- y = LN1(x + v): lane holds (row = g*4+r, c = col / col+16) ---
        const float* xb = x + (size_t)b * (NC * NT);
        float g1a = gamma1[col], be1a = beta1[col];
        float g1b = gamma1[col + 16], be1b = beta1[col + 16];
        #pragma unroll
        for (int r = 0; r < 4; ++r) {
            int t = t0 + (g << 2) + r;
            float v0 = acc0[r] + xb[col * NT + t];
            float v1 = acc1[r] + xb[(col + 16) * NT + t];
            float s = v0 + v1, ss = v0 * v0 + v1 * v1;
            #pragma unroll
            for (int msk = 1; msk < 16; msk <<= 1) {
                s  += __shfl_xor(s, msk);
                ss += __shfl_xor(ss, msk);
            }
            float mean = s * 0.03125f;
            float var = fmaf(-mean, mean, ss * 0.03125f) + 1e-14f;
            float rs = rsqrtf(var);
            y0[r] = (v0 - mean) * rs * g1a + be1a;
            y1[r] = (v1 - mean) * rs * g1b + be1b;
            int rowl = (g << 2) + r;
            ysh[rowl * 40 + col]      = f2bf(y0[r]);
            ysh[rowl * 40 + col + 16] = f2bf(y1[r]);
        }
    }
    __syncthreads();

    v4f h1acc[8];
    if (wv == 0) {
        // --- h1 = relu(y @ W1^T + b1): K=32, 8 n-tiles ---
        #pragma unroll
        for (int nt = 0; nt < 8; ++nt) h1acc[nt] = (v4f){0.f, 0.f, 0.f, 0.f};
        v8s ya = *(const v8s*)(ysh + col * 40 + (g << 3));   // A-frag: m=col, k=g*8+j
        #pragma unroll
        for (int nt = 0; nt < 8; ++nt) {
            v8s wb = *(const v8s*)(w1bf + ((nt << 4) + col) * NC + (g << 3));
            h1acc[nt] = __builtin_amdgcn_mfma_f32_16x16x32_bf16(ya, wb, h1acc[nt], 0, 0, 0);
        }
        #pragma unroll
        for (int nt = 0; nt < 8; ++nt) {
            float bb = b1[(nt << 4) + col];
            #pragma unroll
            for (int r = 0; r < 4; ++r) {
                float hv = fmaxf(h1acc[nt][r] + bb, 0.f);
                h1sh[((g << 2) + r) * 136 + (nt << 4) + col] = f2bf(hv);
            }
        }
    }
    __syncthreads();

    if (wv == 0) {
        // --- h2 = h1 @ W2^T + b2: K=128 (4 k-steps), 2 n-tiles ---
        v4f ha0 = {0.f, 0.f, 0.f, 0.f}, ha1 = {0.f, 0.f, 0.f, 0.f};
        #pragma unroll
        for (int kb2 = 0; kb2 < 4; ++kb2) {
            v8s ha  = *(const v8s*)(h1sh + col * 136 + (kb2 << 5) + (g << 3));
            v8s w0  = *(const v8s*)(w2bf + col * NH + (kb2 << 5) + (g << 3));
            v8s w1v = *(const v8s*)(w2bf + (col + 16) * NH + (kb2 << 5) + (g << 3));
            ha0 = __builtin_amdgcn_mfma_f32_16x16x32_bf16(ha, w0, ha0, 0, 0, 0);
            ha1 = __builtin_amdgcn_mfma_f32_16x16x32_bf16(ha, w1v, ha1, 0, 0, 0);
        }
        // --- y2 = LN2(y + ff), store f32 ---
        float g2a = gamma2[col], be2a = beta2[col];
        float g2b = gamma2[col + 16], be2b = beta2[col + 16];
        float bb0 = b2[col], bb1 = b2[col + 16];
        float* yo = y2out + (size_t)b * (NC * NT);
        #pragma unroll
        for (int r = 0; r < 4; ++r) {
            float z0 = y0[r] + ha0[r] + bb0;
            float z1 = y1[r] + ha1[r] + bb1;
            float s = z0 + z1, ss = z0 * z0 + z1 * z1;
            #pragma unroll
            for (int msk = 1; msk < 16; msk <<= 1) {
                s  += __shfl_xor(s, msk);
                ss += __shfl_xor(ss, msk);
            }
            float mean = s * 0.03125f;
            float var = fmaf(-mean, mean, ss * 0.03125f) + 1e-14f;
            float rs = rsqrtf(var);
            int t = t0 + (g << 2) + r;
            yo[col * NT + t]        = (z0 - mean) * rs * g2a + be2a;
            yo[(col + 16) * NT + t] = (z1 - mean) * rs * g2b + be2b;
        }
    }
}

extern "C" void kernel_launch(void* const* d_in, const int* in_sizes, int n_in,
                              void* d_out, int out_size, void* d_ws, size_t ws_size,
                              hipStream_t stream)
{
    const float* x      = (const float*)d_in[0];
    const float* Wt     = (const float*)d_in[1];
    const float* Wx     = (const float*)d_in[2];
    const float* bh     = (const float*)d_in[3];
    const float* Wa     = (const float*)d_in[4];
    // d_in[5] = ba: cancels identically in softmax (max-shift), not needed
    const float* gamma1 = (const float*)d_in[6];
    const float* beta1  = (const float*)d_in[7];
    const float* W1     = (const float*)d_in[8];
    const float* b1     = (const float*)d_in[9];
    const float* W2     = (const float*)d_in[10];
    const float* b2     = (const float*)d_in[11];
    const float* gamma2 = (const float*)d_in[12];
    const float* beta2  = (const float*)d_in[13];

    char* ws = (char*)d_ws;
    unsigned short* Fq   = (unsigned short*)(ws);             // 4096*192 bf16 = 1.5 MB
    unsigned short* Fk   = (unsigned short*)(ws + 1572864);   // 1.5 MB
    unsigned short* xbf  = (unsigned short*)(ws + 3145728);   // 256 KB
    unsigned short* w1bf = (unsigned short*)(ws + 3407872);   // 8 KB
    unsigned short* w2bf = (unsigned short*)(ws + 3416064);   // 8 KB
    unsigned short* abf  = (unsigned short*)(ws + 3424256);   // 8 MB

    float* out = (float*)d_out;
    float* y2o = out;            // B*C*T = 131072 f32
    float* a_o = out + 131072;   // B*T*T = 4194304 f32

    prep_kernel<<<644, 256, 0, stream>>>(x, Wt, Wx, bh, Wa, W1, W2,
                                         Fq, Fk, xbf, w1bf, w2bf);
    score_kernel<<<256, 512, 0, stream>>>(Fq, Fk, a_o, abf);
    tail_kernel<<<256, 256, 0, stream>>>(abf, xbf, x, gamma1, beta1, w1bf, b1,
                                         w2bf, b2, gamma2, beta2, y2o);
}

// Round 5
// 110.753 us; speedup vs baseline: 1.0499x; 1.0499x over previous
//
#include <hip/hip_runtime.h>
#include <hip/hip_bf16.h>

typedef short v8s __attribute__((ext_vector_type(8)));
typedef float v4f __attribute__((ext_vector_type(4)));

#define NB 4
#define NC 32
#define NT 1024
#define NU 32
#define NH 128
#define KF 192   // 6 feature groups x 32 u

static __device__ __forceinline__ unsigned short f2bf(float f) {
    unsigned int u = __float_as_uint(f);
    return (unsigned short)((u + 0x7fffu + ((u >> 16) & 1u)) >> 16);  // RNE
}

// ---------------- Kernel A: q/k feature maps (MFMA-fragment-tiled) + bf16 copies ----
// tanh(z) ~= z + C1 z^3 + C2 z^5;  e_ij = sum_u Wa_u tanh(q_iu + k_ju)
// factors as sum_p A_p(q) * B_p(k) over 6 groups (binomial expansion).
// Tiled layout: FT[((tile16*6 + p) << 9) + (u>>3)*128 + (row&15)*8 + (u&7)]
// so one wave's MFMA fragment = 64 lanes x 16 B contiguous (1 KB).
__global__ __launch_bounds__(256) void prep_kernel(
    const float* __restrict__ x, const float* __restrict__ Wt,
    const float* __restrict__ Wx, const float* __restrict__ bh,
    const float* __restrict__ Wa,
    const float* __restrict__ W1, const float* __restrict__ W2,
    unsigned short* __restrict__ FqT, unsigned short* __restrict__ FkT,
    unsigned short* __restrict__ xbf,
    unsigned short* __restrict__ w1bf, unsigned short* __restrict__ w2bf)
{
    int bid = blockIdx.x, tid = threadIdx.x;
    if (bid < 512) {
        int gid = (bid << 8) + tid;
        int row = gid >> 5, u = gid & 31;        // row = b*1024 + t
        int b = row >> 10, t = row & 1023;
        const float* xp = x + (size_t)b * (NC * NT) + t;
        float aq = 0.f, ak = 0.f;
        #pragma unroll
        for (int c = 0; c < NC; ++c) {
            float xv = xp[c * NT];
            aq = fmaf(xv, Wt[c * NU + u], aq);
            ak = fmaf(xv, Wx[c * NU + u], ak);
        }
        float q = aq + bh[u];
        float k = ak;
        float wa = Wa[u];
        const float C1 = -0.33333334f, C2 = 0.13333334f;
        int tile = row >> 4;
        size_t fbase = ((size_t)(tile * 6) << 9) + ((u >> 3) << 7) + ((row & 15) << 3) + (u & 7);
        float q2 = q * q, q3 = q2 * q, q4 = q2 * q2, q5 = q4 * q;
        unsigned short* fq = FqT + fbase;
        fq[0]        = f2bf(wa * fmaf(C2, q5, fmaf(C1, q3, q)));
        fq[1 << 9]   = f2bf(wa * fmaf(5.f * C2, q4, fmaf(3.f * C1, q2, 1.f)));
        fq[2 << 9]   = f2bf(wa * fmaf(10.f * C2, q3, 3.f * C1 * q));
        fq[3 << 9]   = f2bf(wa * fmaf(10.f * C2, q2, C1));
        fq[4 << 9]   = f2bf(wa * (5.f * C2 * q));
        fq[5 << 9]   = f2bf(wa * C2);
        float k2 = k * k, k3 = k2 * k, k4 = k2 * k2, k5 = k4 * k;
        unsigned short* fk = FkT + fbase;
        fk[0]        = 0x3F80;            // 1.0 bf16
        fk[1 << 9]   = f2bf(k);
        fk[2 << 9]   = f2bf(k2);
        fk[3 << 9]   = f2bf(k3);
        fk[4 << 9]   = f2bf(k4);
        fk[5 << 9]   = f2bf(k5);
    } else if (bid < 640) {                      // x -> bf16, same [b][c][t] layout
        int base = ((bid - 512) << 10) + (tid << 2);
        float4 xv = *(const float4*)(x + base);
        xbf[base]     = f2bf(xv.x);
        xbf[base + 1] = f2bf(xv.y);
        xbf[base + 2] = f2bf(xv.z);
        xbf[base + 3] = f2bf(xv.w);
    } else if (bid < 642) {                      // W1 (128x32) -> bf16
        int base = ((bid - 640) << 11) + (tid << 3);
        #pragma unroll
        for (int i = 0; i < 8; ++i) w1bf[base + i] = f2bf(W1[base + i]);
    } else {                                     // W2 (32x128) -> bf16
        int base = ((bid - 642) << 11) + (tid << 3);
        #pragma unroll
        for (int i = 0; i < 8; ++i) w2bf[base + i] = f2bf(W2[base + i]);
    }
}

// ---------------- Kernel B: e = Fq @ Fk^T (MFMA), softmax, write a ----------------
// Block = 512 threads (8 waves) owns 16 rows x 1024 cols; wave w owns cols
// [w*128, w*128+128) as 8 n-tiles of 16x16x32 MFMA, K=192 (6 k-steps).
// All fragment loads are contiguous 1-KB global_load_dwordx4 (tiled layout).
__global__ __launch_bounds__(512) void score_kernel(
    const unsigned short* __restrict__ FqT, const unsigned short* __restrict__ FkT,
    float* __restrict__ a_out, unsigned short* __restrict__ abf)
{
    __shared__ float redA[8][16];
    __shared__ float redB[8][16];
    const int tid = threadIdx.x;
    const int lane = tid & 63, w = tid >> 6;
    const int col = lane & 15, g = lane >> 4;
    const int row0 = blockIdx.x << 4;            // global row = b*1024 + t0
    const int b = row0 >> 10;
    const int jbase = w << 7;

    // A-fragments: lane holds A[m=col][k=g*8+j], 6 k-steps, reused over 8 n-tiles
    v8s afr[6];
    {
        const unsigned short* ap = FqT + (((size_t)blockIdx.x * 6) << 9) + (lane << 3);
        #pragma unroll
        for (int ks = 0; ks < 6; ++ks) afr[ks] = *(const v8s*)(ap + (ks << 9));
    }

    v4f acc[8];
    #pragma unroll
    for (int nt = 0; nt < 8; ++nt) acc[nt] = (v4f){0.f, 0.f, 0.f, 0.f};
    {
        // j-tile index: b*64 + w*8 + nt
        const unsigned short* bp = FkT + (((size_t)((b << 6) + (w << 3)) * 6) << 9) + (lane << 3);
        #pragma unroll
        for (int nt = 0; nt < 8; ++nt) {
            const unsigned short* bpn = bp + nt * (6 << 9);
            #pragma unroll
            for (int ks = 0; ks < 6; ++ks) {
                v8s bfr = *(const v8s*)(bpn + (ks << 9));
                acc[nt] = __builtin_amdgcn_mfma_f32_16x16x32_bf16(afr[ks], bfr, acc[nt], 0, 0, 0);
            }
        }
    }

    // ---- softmax over j (rows held as row=g*4+r, col=w*128+nt*16+col) ----
    float m4[4];
    #pragma unroll
    for (int r = 0; r < 4; ++r) {
        float m = acc[0][r];
        #pragma unroll
        for (int nt = 1; nt < 8; ++nt) m = fmaxf(m, acc[nt][r]);
        #pragma unroll
        for (int o = 1; o < 16; o <<= 1) m = fmaxf(m, __shfl_xor(m, o));
        m4[r] = m;
    }
    if (col == 0) {
        #pragma unroll
        for (int r = 0; r < 4; ++r) redA[w][(g << 2) + r] = m4[r];
    }
    __syncthreads();
    float mfin[4];
    #pragma unroll
    for (int r = 0; r < 4; ++r) {
        float m = -1e30f;
        #pragma unroll
        for (int w2 = 0; w2 < 8; ++w2) m = fmaxf(m, redA[w2][(g << 2) + r]);
        mfin[r] = m;
    }
    float s4[4] = {0.f, 0.f, 0.f, 0.f};
    #pragma unroll
    for (int nt = 0; nt < 8; ++nt) {
        #pragma unroll
        for (int r = 0; r < 4; ++r) {
            float ev = __expf(acc[nt][r] - mfin[r]);
            acc[nt][r] = ev;
            s4[r] += ev;
        }
    }
    #pragma unroll
    for (int r = 0; r < 4; ++r) {
        #pragma unroll
        for (int o = 1; o < 16; o <<= 1) s4[r] += __shfl_xor(s4[r], o);
    }
    if (col == 0) {
        #pragma unroll
        for (int r = 0; r < 4; ++r) redB[w][(g << 2) + r] = s4[r];
    }
    __syncthreads();
    float inv[4];
    #pragma unroll
    for (int r = 0; r < 4; ++r) {
        float S = 0.f;
        #pragma unroll
        for (int w2 = 0; w2 < 8; ++w2) S += redB[w2][(g << 2) + r];
        inv[r] = 1.f / (S + 1e-5f);
    }

    #pragma unroll
    for (int r = 0; r < 4; ++r) {
        size_t base = ((size_t)(row0 + (g << 2) + r) << 10) + jbase + col;
        #pragma unroll
        for (int nt = 0; nt < 8; ++nt) {
            float av = acc[nt][r] * inv[r];
            a_out[base + (nt << 4)] = av;
            abf[base + (nt << 4)]   = f2bf(av);
        }
    }
}

// ---------------- Kernel C: v = a@xt (MFMA, 4-wave K-split) -> LN1 -> FFN -> LN2 ----
// Block = 256 threads (4 waves), one 16-row tile. FFN spread across all 4 waves.
__global__ __launch_bounds__(256) void tail_kernel(
    const unsigned short* __restrict__ abf,
    const unsigned short* __restrict__ xbf,
    const float* __restrict__ x,
    const float* __restrict__ gamma1, const float* __restrict__ beta1,
    const unsigned short* __restrict__ w1bf, const float* __restrict__ b1,
    const unsigned short* __restrict__ w2bf, const float* __restrict__ b2,
    const float* __restrict__ gamma2, const float* __restrict__ beta2,
    float* __restrict__ y2out)
{
    __shared__ __attribute__((aligned(16))) float red[4 * 64 * 9];          // padded, 9.2 KB
    __shared__ __attribute__((aligned(16))) unsigned short ysh[16 * 40];    // y bf16
    __shared__ __attribute__((aligned(16))) unsigned short h1sh[16 * 136];  // h1 bf16
    const int tid = threadIdx.x;
    const int lane = tid & 63;
    const int wv = tid >> 6;
    const int col = lane & 15, g = lane >> 4;
    const int b = blockIdx.x >> 6;
    const int t0 = (blockIdx.x & 63) << 4;

    // --- v partial: wave wv covers K-chunks [wv*8, wv*8+8) of 32 ---
    v4f acc0 = {0.f, 0.f, 0.f, 0.f}, acc1 = {0.f, 0.f, 0.f, 0.f};
    {
        const unsigned short* ar  = abf + (((size_t)((b << 10) + t0 + col)) << 10) + (g << 3);
        const unsigned short* xr0 = xbf + (((size_t)((b << 5) + col)) << 10) + (g << 3);
        const unsigned short* xr1 = xr0 + (16 << 10);
        const int it0 = wv << 3;
        #pragma unroll
        for (int i = 0; i < 8; ++i) {
            int it = it0 + i;
            v8s af  = *(const v8s*)(ar  + (it << 5));
            v8s bf0 = *(const v8s*)(xr0 + (it << 5));
            v8s bf1 = *(const v8s*)(xr1 + (it << 5));
            acc0 = __builtin_amdgcn_mfma_f32_16x16x32_bf16(af, bf0, acc0, 0, 0, 0);
            acc1 = __builtin_amdgcn_mfma_f32_16x16x32_bf16(af, bf1, acc1, 0, 0, 0);
        }
    }
    {
        float* rp = red + ((wv << 6) + lane) * 9;
        #pragma unroll
        for (int r = 0; r < 4; ++r) { rp[r] = acc0[r]; rp[4 + r] = acc1[r]; }
    }
    __syncthreads();

    // --- all waves: full v = sum of 4 partials; LN1 (redundant but parallel) ---
    float y0[4], y1[4];
    {
        v4f s0 = {0.f, 0.f, 0.f, 0.f}, s1 = {0.f, 0.f, 0.f, 0.f};
        #pragma unroll
        for (int w2 = 0; w2 < 4; ++w2) {
            const float* rp = red + ((w2 << 6) + lane) * 9;
            #pragma unroll
            for (int r = 0; r < 4; ++r) { s0[r] += rp[r]; s1[r] += rp[4 + r]; }
        }
        const float* xb = x + (size_t)b * (NC * NT);
        float g1a = gamma1[col], be1a = beta1[col];
        float g1b = gamma1[col + 16], be1b = beta1[col + 16];
        #pragma unroll
        for (int r = 0; r < 4; ++r) {
            int t = t0 + (g << 2) + r;
            float v0 = s0[r] + xb[col * NT + t];
            float v1 = s1[r] + xb[(col + 16) * NT + t];
            float s = v0 + v1, ss = v0 * v0 + v1 * v1;
            #pragma unroll
            for (int msk = 1; msk < 16; msk <<= 1) {
                s  += __shfl_xor(s, msk);
                ss += __shfl_xor(ss, msk);
            }
            float mean = s * 0.03125f;
            float var = fmaf(-mean, mean, ss * 0.03125f) + 1e-14f;
            float rs = rsqrtf(var);
            y0[r] = (v0 - mean) * rs * g1a + be1a;
            y1[r] = (v1 - mean) * rs * g1b + be1b;
            if (wv == 0) {
                int rowl = (g << 2) + r;
                ysh[rowl * 40 + col]      = f2bf(y0[r]);
                ysh[rowl * 40 + col + 16] = f2bf(y1[r]);
            }
        }
    }
    __syncthreads();

    // --- h1 = relu(y @ W1^T + b1): K=32, wave wv does n-tiles {2wv, 2wv+1} ---
    {
        v8s ya = *(const v8s*)(ysh + col * 40 + (g << 3));   // A-frag: m=col, k=g*8+j
        #pragma unroll
        for (int i = 0; i < 2; ++i) {
            int nt = (wv << 1) + i;
            v4f hacc = {0.f, 0.f, 0.f, 0.f};
            v8s wb = *(const v8s*)(w1bf + ((nt << 4) + col) * NC + (g << 3));
            hacc = __builtin_amdgcn_mfma_f32_16x16x32_bf16(ya, wb, hacc, 0, 0, 0);
            float bb = b1[(nt << 4) + col];
            #pragma unroll
            for (int r = 0; r < 4; ++r) {
                float hv = fmaxf(hacc[r] + bb, 0.f);
                h1sh[((g << 2) + r) * 136 + (nt << 4) + col] = f2bf(hv);
            }
        }
    }
    __syncthreads();

    // --- h2 partial: wave wv does k-step kb2=wv (K=128 split 4 ways), 2 n-tiles ---
    {
        v4f ha0 = {0.f, 0.f, 0.f, 0.f}, ha1 = {0.f, 0.f, 0.f, 0.f};
        v8s ha  = *(const v8s*)(h1sh + col * 136 + (wv << 5) + (g << 3));
        v8s w0  = *(const v8s*)(w2bf + col * NH + (wv << 5) + (g << 3));
        v8s w1v = *(const v8s*)(w2bf + (col + 16) * NH + (wv << 5) + (g << 3));
        ha0 = __builtin_amdgcn_mfma_f32_16x16x32_bf16(ha, w0, ha0, 0, 0, 0);
        ha1 = __builtin_amdgcn_mfma_f32_16x16x32_bf16(ha, w1v, ha1, 0, 0, 0);
        float* rp = red + ((wv << 6) + lane) * 9;
        #pragma unroll
        for (int r = 0; r < 4; ++r) { rp[r] = ha0[r]; rp[4 + r] = ha1[r]; }
    }
    __syncthreads();

    if (wv == 0) {
        // --- sum h2 partials; y2 = LN2(y + ff); store f32 ---
        v4f ha0 = {0.f, 0.f, 0.f, 0.f}, ha1 = {0.f, 0.f, 0.f, 0.f};
        #pragma unroll
        for (int w2 = 0; w2 < 4; ++w2) {
            const float* rp = red + ((w2 << 6) + lane) * 9;
            #pragma unroll
            for (int r = 0; r < 4; ++r) { ha0[r] += rp[r]; ha1[r] += rp[4 + r]; }
        }
        float g2a = gamma2[col], be2a = beta2[col];
        float g2b = gamma2[col + 16], be2b = beta2[col + 16];
        float bb0 = b2[col], bb1 = b2[col + 16];
        float* yo = y2out + (size_t)b * (NC * NT);
        #pragma unroll
        for (int r = 0; r < 4; ++r) {
            float z0 = y0[r] + ha0[r] + bb0;
            float z1 = y1[r] + ha1[r] + bb1;
            float s = z0 + z1, ss = z0 * z0 + z1 * z1;
            #pragma unroll
            for (int msk = 1; msk < 16; msk <<= 1) {
                s  += __shfl_xor(s, msk);
                ss += __shfl_xor(ss, msk);
            }
            float mean = s * 0.03125f;
            float var = fmaf(-mean, mean, ss * 0.03125f) + 1e-14f;
            float rs = rsqrtf(var);
            int t = t0 + (g << 2) + r;
            yo[col * NT + t]        = (z0 - mean) * rs * g2a + be2a;
            yo[(col + 16) * NT + t] = (z1 - mean) * rs * g2b + be2b;
        }
    }
}

extern "C" void kernel_launch(void* const* d_in, const int* in_sizes, int n_in,
                              void* d_out, int out_size, void* d_ws, size_t ws_size,
                              hipStream_t stream)
{
    const float* x      = (const float*)d_in[0];
    const float* Wt     = (const float*)d_in[1];
    const float* Wx     = (const float*)d_in[2];
    const float* bh     = (const float*)d_in[3];
    const float* Wa     = (const float*)d_in[4];
    // d_in[5] = ba: cancels identically in softmax (max-shift), not needed
    const float* gamma1 = (const float*)d_in[6];
    const float* beta1  = (const float*)d_in[7];
    const float* W1     = (const float*)d_in[8];
    const float* b1     = (const float*)d_in[9];
    const float* W2     = (const float*)d_in[10];
    const float* b2     = (const float*)d_in[11];
    const float* gamma2 = (const float*)d_in[12];
    const float* beta2  = (const float*)d_in[13];

    char* ws = (char*)d_ws;
    unsigned short* FqT  = (unsigned short*)(ws);             // 256 tiles*6*512 bf16 = 1.5 MB
    unsigned short* FkT  = (unsigned short*)(ws + 1572864);   // 1.5 MB
    unsigned short* xbf  = (unsigned short*)(ws + 3145728);   // 256 KB
    unsigned short* w1bf = (unsigned short*)(ws + 3407872);   // 8 KB
    unsigned short* w2bf = (unsigned short*)(ws + 3416064);   // 8 KB
    unsigned short* abf  = (unsigned short*)(ws + 3424256);   // 8 MB

    float* out = (float*)d_out;
    float* y2o = out;            // B*C*T = 131072 f32
    float* a_o = out + 131072;   // B*T*T = 4194304 f32

    prep_kernel<<<644, 256, 0, stream>>>(x, Wt, Wx, bh, Wa, W1, W2,
                                         FqT, FkT, xbf, w1bf, w2bf);
    score_kernel<<<256, 512, 0, stream>>>(FqT, FkT, a_o, abf);
    tail_kernel<<<256, 256, 0, stream>>>(abf, xbf, x, gamma1, beta1, w1bf, b1,
                                         w2bf, b2, gamma2, beta2, y2o);
}

// Round 6
// 102.949 us; speedup vs baseline: 1.1294x; 1.0758x over previous
//
#include <hip/hip_runtime.h>
#include <hip/hip_bf16.h>

typedef short v8s __attribute__((ext_vector_type(8)));
typedef float v4f __attribute__((ext_vector_type(4)));

#define NB 4
#define NC 32
#define NT 1024
#define NU 32
#define NH 128

static __device__ __forceinline__ unsigned short f2bf(float f) {
    unsigned int u = __float_as_uint(f);
    return (unsigned short)((u + 0x7fffu + ((u >> 16) & 1u)) >> 16);  // RNE
}

// ---------------- Kernel A: k feature maps (fragment-tiled) + tiled x + weights ----
// tanh(z) ~= z + C1 z^3 + C2 z^5; e_ij = sum_u Wa_u tanh(q_iu+k_ju) factors into
// K=192 GEMM. FkT fragment layout (verified R5): plane p of j-tile T at
// FkT[(T*6+p)*512 + lane*8 + idx], lane=(u>>3)*16+(j&15), idx=u&7.
// xT fragment layout: (b,ct,it) at xT[((b*2+ct)*32+it)*512 + lane*8 + idx],
// lane=(c&15)+16*((j>>3)&3), idx=j&7  (B-operand of 16x16x32 MFMA).
__global__ __launch_bounds__(256) void prep_kernel(
    const float* __restrict__ x, const float* __restrict__ Wx,
    const float* __restrict__ W1, const float* __restrict__ W2,
    unsigned short* __restrict__ FkT, unsigned short* __restrict__ xT,
    unsigned short* __restrict__ w1bf, unsigned short* __restrict__ w2bf)
{
    int bid = blockIdx.x, tid = threadIdx.x;
    if (bid < 512) {
        int gid = (bid << 8) + tid;
        int row = gid >> 5, u = gid & 31;        // row = b*1024 + j
        int b = row >> 10;
        const float* xp = x + (size_t)b * (NC * NT) + (row & 1023);
        float ak = 0.f;
        #pragma unroll
        for (int c = 0; c < NC; ++c) ak = fmaf(xp[c * NT], Wx[c * NU + u], ak);
        float k = ak;
        int tile = row >> 4;
        size_t fbase = ((size_t)(tile * 6) << 9) + ((u >> 3) << 7) + ((row & 15) << 3) + (u & 7);
        float k2 = k * k, k3 = k2 * k, k4 = k2 * k2, k5 = k4 * k;
        unsigned short* fk = FkT + fbase;
        fk[0]    = 0x3F80;            // 1.0 bf16
        fk[512]  = f2bf(k);
        fk[1024] = f2bf(k2);
        fk[1536] = f2bf(k3);
        fk[2048] = f2bf(k4);
        fk[2560] = f2bf(k5);
    } else if (bid < 576) {                      // x -> bf16 fragment-tiled
        int ch = ((bid - 512) << 8) + tid;       // [0, 16384) 8-elem chunks
        int j0 = (ch & 127) << 3, c = (ch >> 7) & 31, b = ch >> 12;
        const float* xp = x + ((size_t)(b * NC + c) << 10) + j0;
        float4 xa = *(const float4*)xp;
        float4 xb = *(const float4*)(xp + 4);
        v8s vv;
        vv[0] = (short)f2bf(xa.x); vv[1] = (short)f2bf(xa.y);
        vv[2] = (short)f2bf(xa.z); vv[3] = (short)f2bf(xa.w);
        vv[4] = (short)f2bf(xb.x); vv[5] = (short)f2bf(xb.y);
        vv[6] = (short)f2bf(xb.z); vv[7] = (short)f2bf(xb.w);
        int it = j0 >> 5;
        int lanep = (c & 15) + (((j0 >> 3) & 3) << 4);
        *(v8s*)(xT + ((size_t)((((b << 1) + (c >> 4)) << 5) + it) << 9) + (lanep << 3)) = vv;
    } else if (bid == 576) {                     // W1 (128x32) -> bf16
        int base = tid << 4;
        #pragma unroll
        for (int i = 0; i < 16; ++i) w1bf[base + i] = f2bf(W1[base + i]);
    } else {                                     // W2 (32x128) -> bf16
        int base = tid << 4;
        #pragma unroll
        for (int i = 0; i < 16; ++i) w2bf[base + i] = f2bf(W2[base + i]);
    }
}

// ---------------- Kernel B (fused): q-feat -> score GEMM -> softmax -> v -> LN1
//                  -> FFN -> LN2.  Block = 512 thr (8 waves) owns 16 t-rows.
__global__ __launch_bounds__(512) void fused_kernel(
    const float* __restrict__ x, const float* __restrict__ Wt,
    const float* __restrict__ bh, const float* __restrict__ Wa,
    const unsigned short* __restrict__ FkT, const unsigned short* __restrict__ xT,
    const float* __restrict__ gamma1, const float* __restrict__ beta1,
    const unsigned short* __restrict__ w1bf, const float* __restrict__ b1,
    const unsigned short* __restrict__ w2bf, const float* __restrict__ b2,
    const float* __restrict__ gamma2, const float* __restrict__ beta2,
    float* __restrict__ a_out, float* __restrict__ y2out)
{
    __shared__ __attribute__((aligned(16))) unsigned short fq[6 * 512];   // 6 KB
    __shared__ __attribute__((aligned(16))) unsigned short ash[32 * 512]; // 32 KB a-tile
    __shared__ float redA[8][16];
    __shared__ float redB[8][16];
    __shared__ __attribute__((aligned(16))) float red[8 * 8 * 64];        // 16 KB
    __shared__ __attribute__((aligned(16))) unsigned short ysh[16 * 40];
    __shared__ __attribute__((aligned(16))) unsigned short h1sh[16 * 136];

    const int tid = threadIdx.x, lane = tid & 63, w = tid >> 6;
    const int col = lane & 15, g = lane >> 4;
    const int bI = blockIdx.x;
    const int b = bI >> 6, t0 = (bI & 63) << 4;

    // ---- phase 0: q features for this block's 16 rows -> LDS (A-frag layout) ----
    {
        int rl = tid >> 5, u = tid & 31;
        const float* xp = x + (size_t)b * (NC * NT) + t0 + rl;
        float aq = 0.f;
        #pragma unroll
        for (int c = 0; c < NC; ++c) aq = fmaf(xp[c * NT], Wt[c * NU + u], aq);
        float q = aq + bh[u];
        float wa = Wa[u];
        const float C1 = -0.33333334f, C2 = 0.13333334f;
        float q2 = q * q, q3 = q2 * q, q4 = q2 * q2, q5 = q4 * q;
        unsigned short* fqp = fq + ((u >> 3) << 7) + (rl << 3) + (u & 7);
        fqp[0]    = f2bf(wa * fmaf(C2, q5, fmaf(C1, q3, q)));
        fqp[512]  = f2bf(wa * fmaf(5.f * C2, q4, fmaf(3.f * C1, q2, 1.f)));
        fqp[1024] = f2bf(wa * fmaf(10.f * C2, q3, 3.f * C1 * q));
        fqp[1536] = f2bf(wa * fmaf(10.f * C2, q2, C1));
        fqp[2048] = f2bf(wa * (5.f * C2 * q));
        fqp[2560] = f2bf(wa * C2);
    }
    __syncthreads();

    // ---- phase 1: e = Fq @ Fk^T, K=192; wave w owns cols [w*128, w*128+128) ----
    v8s afr[6];
    #pragma unroll
    for (int ks = 0; ks < 6; ++ks) afr[ks] = *(const v8s*)(fq + (ks << 9) + (lane << 3));

    v4f acc[8];
    #pragma unroll
    for (int nt = 0; nt < 8; ++nt) acc[nt] = (v4f){0.f, 0.f, 0.f, 0.f};
    {
        const unsigned short* bp = FkT + (((size_t)((b << 6) + (w << 3)) * 6) << 9) + (lane << 3);
        #pragma unroll
        for (int nt = 0; nt < 8; ++nt) {
            const unsigned short* bpn = bp + nt * (6 << 9);
            #pragma unroll
            for (int ks = 0; ks < 6; ++ks) {
                v8s bfr = *(const v8s*)(bpn + (ks << 9));
                acc[nt] = __builtin_amdgcn_mfma_f32_16x16x32_bf16(afr[ks], bfr, acc[nt], 0, 0, 0);
            }
        }
    }

    // ---- softmax over j ----
    float m4[4];
    #pragma unroll
    for (int r = 0; r < 4; ++r) {
        float m = acc[0][r];
        #pragma unroll
        for (int nt = 1; nt < 8; ++nt) m = fmaxf(m, acc[nt][r]);
        #pragma unroll
        for (int o = 1; o < 16; o <<= 1) m = fmaxf(m, __shfl_xor(m, o));
        m4[r] = m;
    }
    if (col == 0) {
        #pragma unroll
        for (int r = 0; r < 4; ++r) redA[w][(g << 2) + r] = m4[r];
    }
    __syncthreads();
    float mfin[4];
    #pragma unroll
    for (int r = 0; r < 4; ++r) {
        float m = -1e30f;
        #pragma unroll
        for (int w2 = 0; w2 < 8; ++w2) m = fmaxf(m, redA[w2][(g << 2) + r]);
        mfin[r] = m;
    }
    float s4[4] = {0.f, 0.f, 0.f, 0.f};
    #pragma unroll
    for (int nt = 0; nt < 8; ++nt) {
        #pragma unroll
        for (int r = 0; r < 4; ++r) {
            float ev = __expf(acc[nt][r] - mfin[r]);
            acc[nt][r] = ev;
            s4[r] += ev;
        }
    }
    #pragma unroll
    for (int r = 0; r < 4; ++r) {
        #pragma unroll
        for (int o = 1; o < 16; o <<= 1) s4[r] += __shfl_xor(s4[r], o);
    }
    if (col == 0) {
        #pragma unroll
        for (int r = 0; r < 4; ++r) redB[w][(g << 2) + r] = s4[r];
    }
    __syncthreads();
    float inv[4];
    #pragma unroll
    for (int r = 0; r < 4; ++r) {
        float S = 0.f;
        #pragma unroll
        for (int w2 = 0; w2 < 8; ++w2) S += redB[w2][(g << 2) + r];
        inv[r] = 1.f / (S + 1e-5f);
    }

    // a: f32 -> d_out; bf16 -> LDS ash in A-fragment layout for the v-GEMM
    #pragma unroll
    for (int r = 0; r < 4; ++r) {
        size_t base = ((size_t)((bI << 4) + (g << 2) + r) << 10) + (w << 7) + col;
        int m = (g << 2) + r;
        #pragma unroll
        for (int nt = 0; nt < 8; ++nt) {
            float av = acc[nt][r] * inv[r];
            a_out[base + (nt << 4)] = av;
            int j = (w << 7) + (nt << 4) + col;
            ash[((j >> 5) << 9) + (((j >> 3) & 3) << 7) + (m << 3) + (j & 7)] = f2bf(av);
        }
    }
    __syncthreads();

    // ---- phase 2: v = a@xt, K=1024 split 8 ways (wave w: it in [w*4, w*4+4)) ----
    {
        v4f v0 = {0.f, 0.f, 0.f, 0.f}, v1 = {0.f, 0.f, 0.f, 0.f};
        #pragma unroll
        for (int i = 0; i < 4; ++i) {
            int it = (w << 2) + i;
            v8s af  = *(const v8s*)(ash + (it << 9) + (lane << 3));
            v8s bf0 = *(const v8s*)(xT + ((size_t)(((b << 1) << 5) + it) << 9) + (lane << 3));
            v8s bf1 = *(const v8s*)(xT + ((size_t)((((b << 1) + 1) << 5) + it) << 9) + (lane << 3));
            v0 = __builtin_amdgcn_mfma_f32_16x16x32_bf16(af, bf0, v0, 0, 0, 0);
            v1 = __builtin_amdgcn_mfma_f32_16x16x32_bf16(af, bf1, v1, 0, 0, 0);
        }
        #pragma unroll
        for (int r = 0; r < 4; ++r) {
            red[(((w << 3) + r) << 6) + lane]     = v0[r];
            red[(((w << 3) + 4 + r) << 6) + lane] = v1[r];
        }
    }
    __syncthreads();

    // ---- LN1 (all waves redundantly; wave 0 stages y to LDS) ----
    float y0[4], y1[4];
    {
        float s0[4] = {0.f, 0.f, 0.f, 0.f}, s1[4] = {0.f, 0.f, 0.f, 0.f};
        #pragma unroll
        for (int w2 = 0; w2 < 8; ++w2) {
            #pragma unroll
            for (int r = 0; r < 4; ++r) {
                s0[r] += red[(((w2 << 3) + r) << 6) + lane];
                s1[r] += red[(((w2 << 3) + 4 + r) << 6) + lane];
            }
        }
        const float* xb = x + (size_t)b * (NC * NT);
        float g1a = gamma1[col], be1a = beta1[col];
        float g1b = gamma1[col + 16], be1b = beta1[col + 16];
        #pragma unroll
        for (int r = 0; r < 4; ++r) {
            int t = t0 + (g << 2) + r;
            float v0 = s0[r] + xb[col * NT + t];
            float v1 = s1[r] + xb[(col + 16) * NT + t];
            float s = v0 + v1, ss = v0 * v0 + v1 * v1;
            #pragma unroll
            for (int msk = 1; msk < 16; msk <<= 1) {
                s  += __shfl_xor(s, msk);
                ss += __shfl_xor(ss, msk);
            }
            float mean = s * 0.03125f;
            float var = fmaf(-mean, mean, ss * 0.03125f) + 1e-14f;
            float rs = rsqrtf(var);
            y0[r] = (v0 - mean) * rs * g1a + be1a;
            y1[r] = (v1 - mean) * rs * g1b + be1b;
            if (w == 0) {
                int rowl = (g << 2) + r;
                ysh[rowl * 40 + col]      = f2bf(y0[r]);
                ysh[rowl * 40 + col + 16] = f2bf(y1[r]);
            }
        }
    }
    __syncthreads();

    // ---- h1 = relu(y @ W1^T + b1): wave w does n-tile w ----
    {
        v8s ya = *(const v8s*)(ysh + col * 40 + (g << 3));
        v4f hacc = {0.f, 0.f, 0.f, 0.f};
        v8s wb = *(const v8s*)(w1bf + ((w << 4) + col) * NC + (g << 3));
        hacc = __builtin_amdgcn_mfma_f32_16x16x32_bf16(ya, wb, hacc, 0, 0, 0);
        float bb = b1[(w << 4) + col];
        #pragma unroll
        for (int r = 0; r < 4; ++r) {
            float hv = fmaxf(hacc[r] + bb, 0.f);
            h1sh[((g << 2) + r) * 136 + (w << 4) + col] = f2bf(hv);
        }
    }
    __syncthreads();

    // ---- h2 partial: wave w -> (ct = w>>2, kb = w&3) ----
    {
        int ct = w >> 2, kb = w & 3;
        v8s ha  = *(const v8s*)(h1sh + col * 136 + (kb << 5) + (g << 3));
        v8s wv2 = *(const v8s*)(w2bf + (col + (ct << 4)) * NH + (kb << 5) + (g << 3));
        v4f hacc = {0.f, 0.f, 0.f, 0.f};
        hacc = __builtin_amdgcn_mfma_f32_16x16x32_bf16(ha, wv2, hacc, 0, 0, 0);
        #pragma unroll
        for (int r = 0; r < 4; ++r) red[(((w << 3) + r) << 6) + lane] = hacc[r];
    }
    __syncthreads();

    if (w == 0) {
        // ---- sum h2 partials; y2 = LN2(y + ff); store f32 ----
        v4f ha0 = {0.f, 0.f, 0.f, 0.f}, ha1 = {0.f, 0.f, 0.f, 0.f};
        #pragma unroll
        for (int w2 = 0; w2 < 4; ++w2) {
            #pragma unroll
            for (int r = 0; r < 4; ++r) {
                ha0[r] += red[(((w2 << 3) + r) << 6) + lane];
                ha1[r] += red[((((w2 + 4) << 3) + r) << 6) + lane];
            }
        }
        float g2a = gamma2[col], be2a = beta2[col];
        float g2b = gamma2[col + 16], be2b = beta2[col + 16];
        float bb0 = b2[col], bb1 = b2[col + 16];
        float* yo = y2out + (size_t)b * (NC * NT);
        #pragma unroll
        for (int r = 0; r < 4; ++r) {
            float z0 = y0[r] + ha0[r] + bb0;
            float z1 = y1[r] + ha1[r] + bb1;
            float s = z0 + z1, ss = z0 * z0 + z1 * z1;
            #pragma unroll
            for (int msk = 1; msk < 16; msk <<= 1) {
                s  += __shfl_xor(s, msk);
                ss += __shfl_xor(ss, msk);
            }
            float mean = s * 0.03125f;
            float var = fmaf(-mean, mean, ss * 0.03125f) + 1e-14f;
            float rs = rsqrtf(var);
            int t = t0 + (g << 2) + r;
            yo[col * NT + t]        = (z0 - mean) * rs * g2a + be2a;
            yo[(col + 16) * NT + t] = (z1 - mean) * rs * g2b + be2b;
        }
    }
}

extern "C" void kernel_launch(void* const* d_in, const int* in_sizes, int n_in,
                              void* d_out, int out_size, void* d_ws, size_t ws_size,
                              hipStream_t stream)
{
    const float* x      = (const float*)d_in[0];
    const float* Wt     = (const float*)d_in[1];
    const float* Wx     = (const float*)d_in[2];
    const float* bh     = (const float*)d_in[3];
    const float* Wa     = (const float*)d_in[4];
    // d_in[5] = ba: cancels identically in softmax (max-shift)
    const float* gamma1 = (const float*)d_in[6];
    const float* beta1  = (const float*)d_in[7];
    const float* W1     = (const float*)d_in[8];
    const float* b1     = (const float*)d_in[9];
    const float* W2     = (const float*)d_in[10];
    const float* b2     = (const float*)d_in[11];
    const float* gamma2 = (const float*)d_in[12];
    const float* beta2  = (const float*)d_in[13];

    char* ws = (char*)d_ws;
    unsigned short* FkT  = (unsigned short*)(ws);             // 786432 bf16 = 1.5 MB
    unsigned short* xT   = (unsigned short*)(ws + 1572864);   // 256 KB
    unsigned short* w1bf = (unsigned short*)(ws + 1835008);   // 8 KB
    unsigned short* w2bf = (unsigned short*)(ws + 1843200);   // 8 KB

    float* out = (float*)d_out;
    float* y2o = out;            // B*C*T = 131072 f32
    float* a_o = out + 131072;   // B*T*T = 4194304 f32

    prep_kernel<<<578, 256, 0, stream>>>(x, Wx, W1, W2, FkT, xT, w1bf, w2bf);
    fused_kernel<<<256, 512, 0, stream>>>(x, Wt, bh, Wa, FkT, xT,
                                          gamma1, beta1, w1bf, b1, w2bf, b2,
                                          gamma2, beta2, a_o, y2o);
}